// Round 5
// baseline (585.015 us; speedup 1.0000x reference)
//
#include <hip/hip_runtime.h>
#include <stdint.h>

// QuantizedLinear: y = x @ quantdequant(w).T + bias   (M=8192, N=4096, K=4096)
//
// Scheme (R4-proven, absmax 0.033 vs 0.146 threshold):
//   prep: wq = bf16(clip(round(w/s),-8,7)*s)  (group-128 absmax scale, folded)
//         xb = bf16(x)
//   qgemm: plain bf16 GEMM (fp32 acc) + bias.  128x128/BK=64 m97-structure,
//          gload_lds(16B) + XOR-swizzle both-sides, sB dbuf, 2 blocks/CU.
// R5 change: ONE grid-stride prep kernel (4096 blocks) replaces two 16k-block
// elementwise kernels (~237us of non-qgemm time vs ~48us memory floor).
// qgemm byte-identical to replay-proven R4.

#define BM 128
#define BN 128
#define BK 64

typedef float    f32x4 __attribute__((ext_vector_type(4)));
typedef uint32_t u32x4 __attribute__((ext_vector_type(4)));
typedef uint32_t u32x2 __attribute__((ext_vector_type(2)));

__device__ __forceinline__ uint16_t f2bf(float f) {
  uint32_t u = __float_as_uint(f);
  uint32_t r = u + 0x7FFFu + ((u >> 16) & 1u);   // RNE, finite inputs
  return (uint16_t)(r >> 16);
}
__device__ __forceinline__ void gload_lds16(const void* g, void* l) {
  __builtin_amdgcn_global_load_lds(
      (const __attribute__((address_space(1))) void*)g,
      (__attribute__((address_space(3))) void*)l, 16, 0, 0);
}
__device__ __forceinline__ void mfma16x16x32bf16(f32x4& d, const u32x4& a, const u32x4& b) {
  asm("v_mfma_f32_16x16x32_bf16 %0, %1, %2, %0" : "+v"(d) : "v"(a), "v"(b));
}

// -------- fused pre-pass: w fake-quant (scale folded) + x -> bf16 ------------
// grid-stride; w granule = 4 floats (32-lane half-wave == one 128-group,
// holds because grid stride is a multiple of 256 granules); x granule = 8.
__global__ void prep(const float* __restrict__ w, uint16_t* __restrict__ wq,
                     size_t wGran, const float* __restrict__ x,
                     uint16_t* __restrict__ xb, size_t xGran) {
  size_t gstride = (size_t)gridDim.x * blockDim.x;
  size_t gtid = (size_t)blockIdx.x * blockDim.x + threadIdx.x;

  for (size_t g = gtid; g < wGran; g += gstride) {
    float4 v = *reinterpret_cast<const float4*>(w + g * 4);
    float a = fmaxf(fmaxf(fabsf(v.x), fabsf(v.y)), fmaxf(fabsf(v.z), fabsf(v.w)));
#pragma unroll
    for (int off = 16; off > 0; off >>= 1) a = fmaxf(a, __shfl_xor(a, off));
    float scale = a / 7.0f;                     // absmax/QMAX, matches ref
    float ss = (scale > 0.0f) ? scale : 1.0f;
    float q0 = fminf(fmaxf(rintf(v.x / ss), -8.0f), 7.0f);  // rintf = RNE = jnp.round
    float q1 = fminf(fmaxf(rintf(v.y / ss), -8.0f), 7.0f);
    float q2 = fminf(fmaxf(rintf(v.z / ss), -8.0f), 7.0f);
    float q3 = fminf(fmaxf(rintf(v.w / ss), -8.0f), 7.0f);
    u32x2 pk = { (uint32_t)f2bf(q0 * scale) | ((uint32_t)f2bf(q1 * scale) << 16),
                 (uint32_t)f2bf(q2 * scale) | ((uint32_t)f2bf(q3 * scale) << 16) };
    *reinterpret_cast<u32x2*>(wq + g * 4) = pk;
  }

  for (size_t g = gtid; g < xGran; g += gstride) {
    const float4* p = reinterpret_cast<const float4*>(x) + g * 2;
    float4 a = p[0], b = p[1];
    float f[8] = {a.x, a.y, a.z, a.w, b.x, b.y, b.z, b.w};
    u32x4 hv = { (uint32_t)f2bf(f[0]) | ((uint32_t)f2bf(f[1]) << 16),
                 (uint32_t)f2bf(f[2]) | ((uint32_t)f2bf(f[3]) << 16),
                 (uint32_t)f2bf(f[4]) | ((uint32_t)f2bf(f[5]) << 16),
                 (uint32_t)f2bf(f[6]) | ((uint32_t)f2bf(f[7]) << 16) };
    *reinterpret_cast<u32x4*>(xb + g * 8) = hv;
  }
}

// ------------------------------- GEMM (byte-identical to R4) -----------------
__global__ __launch_bounds__(256, 2) void qgemm(
    const uint16_t* __restrict__ xb, const uint16_t* __restrict__ wq,
    const float* __restrict__ bias, float* __restrict__ out,
    int M, int N, int K) {
  __shared__ uint16_t sA[BM * BK];       // 16 KB
  __shared__ uint16_t sB[2][BN * BK];    // 32 KB

  const int tid = threadIdx.x;
  const int lane = tid & 63;
  const int wid = tid >> 6;
  const int wm = wid >> 1;
  const int wn = wid & 1;

  int nblkTotal = N / BN;
  int bid = (int)blockIdx.x;
  int nwg = (int)gridDim.x;
  int id = bid;
  if ((nwg & 7) == 0) { int cpx = nwg >> 3; id = (bid & 7) * cpx + (bid >> 3); }
  const int mbase = (id / nblkTotal) * BM;
  const int nbase = (id % nblkTotal) * BN;
  const int nt = K / BK;

  const uint16_t* ap = xb + (size_t)mbase * K;
  const uint16_t* bp = wq + (size_t)nbase * K;

  f32x4 acc[4][4] = {};

  auto issuePlane = [&](const uint16_t* src0, uint16_t* lds, int t) {
#pragma unroll
    for (int i = 0; i < 4; ++i) {
      int gran = i * 256 + tid;                 // 16B granule index
      int row = gran >> 3;
      int slot = gran & 7;
      const uint16_t* src = src0 + (size_t)row * K + (size_t)t * BK
                                 + ((slot ^ (row & 7)) << 3);
      gload_lds16(src, &lds[(size_t)(i * 256 + wid * 64) * 8]); // wave-uniform base
    }
  };

  auto computeTile = [&](int buf) {
#pragma unroll
    for (int kk = 0; kk < 2; ++kk) {
      u32x4 av[4], bv[4];
#pragma unroll
      for (int i = 0; i < 4; ++i) {
        int row = wm * 64 + i * 16 + (lane & 15);
        int slot = kk * 4 + (lane >> 4);
        int boff = row * 128 + ((slot ^ (row & 7)) << 4);
        av[i] = *reinterpret_cast<const u32x4*>(reinterpret_cast<const char*>(sA) + boff);
      }
#pragma unroll
      for (int j = 0; j < 4; ++j) {
        int row = wn * 64 + j * 16 + (lane & 15);
        int slot = kk * 4 + (lane >> 4);
        int boff = row * 128 + ((slot ^ (row & 7)) << 4);
        bv[j] = *reinterpret_cast<const u32x4*>(reinterpret_cast<const char*>(sB[buf]) + boff);
      }
#pragma unroll
      for (int i = 0; i < 4; ++i)
#pragma unroll
        for (int j = 0; j < 4; ++j)
          mfma16x16x32bf16(acc[i][j], av[i], bv[j]);
    }
  };

  // prologue: stage tile 0
  issuePlane(bp, sB[0], 0);
  issuePlane(ap, sA,    0);
  __syncthreads();                       // implicit vmcnt(0) drain

  int cur = 0;
  for (int t = 0; t < nt; ++t) {
    if (t + 1 < nt) issuePlane(bp, sB[cur ^ 1], t + 1);  // prefetch, hides under MFMA
    computeTile(cur);
    __syncthreads();                     // all waves done reading sA(t)
    if (t + 1 < nt) issuePlane(ap, sA, t + 1);
    __syncthreads();                     // vmcnt drained -> tile t+1 ready
    cur ^= 1;
  }

  // epilogue: C/D layout col = lane&15, row = (lane>>4)*4 + r  (verified R1)
#pragma unroll
  for (int j = 0; j < 4; ++j) {
    int n = nbase + wn * 64 + j * 16 + (lane & 15);
    float b = bias[n];
#pragma unroll
    for (int i = 0; i < 4; ++i) {
      int m0 = mbase + wm * 64 + i * 16 + ((lane >> 4) << 2);
#pragma unroll
      for (int r = 0; r < 4; ++r)
        out[(size_t)(m0 + r) * N + n] = acc[i][j][r] + b;
    }
  }
}

extern "C" void kernel_launch(void* const* d_in, const int* in_sizes, int n_in,
                              void* d_out, int out_size, void* d_ws, size_t ws_size,
                              hipStream_t stream) {
  const float* x = (const float*)d_in[0];
  const float* w = (const float*)d_in[1];
  const float* bias = (const float*)d_in[2];
  float* out = (float*)d_out;

  int N = in_sizes[2];                   // 4096
  int K = in_sizes[1] / N;               // 4096
  int M = in_sizes[0] / K;               // 8192

  size_t wqB = (size_t)N * K * sizeof(uint16_t);   // 32 MiB
  uint16_t* wq = (uint16_t*)d_ws;
  uint16_t* xb = (uint16_t*)((char*)d_ws + wqB);   // 64 MiB

  size_t wGran = (size_t)N * K / 4;
  size_t xGran = (size_t)M * K / 8;
  prep<<<4096, 256, 0, stream>>>(w, wq, wGran, x, xb, xGran);

  dim3 grid((M / BM) * (N / BN));
  qgemm<<<grid, 256, 0, stream>>>(xb, wq, bias, out, M, N, K);
}